// Round 1
// baseline (939.079 us; speedup 1.0000x reference)
//
#include <hip/hip_runtime.h>

#define D_MODEL 1024
#define NHEADS  16
#define DKH     64
#define BATCH   2
#define SEQ     2048
#define MTOT    (BATCH*SEQ)     // 4096
#define NQKV    (3*D_MODEL)     // 3072
#define LDT     72              // 64 + 8 pad (ushorts) -> 144B row stride (GEMM kernels)
#define LDP     72              // P-transpose LDS row stride (ushorts)

typedef __bf16 bf16x8 __attribute__((ext_vector_type(8)));
typedef float  f32x4  __attribute__((ext_vector_type(4)));
typedef unsigned short u16x8 __attribute__((ext_vector_type(8)));
typedef unsigned short u16x4 __attribute__((ext_vector_type(4)));

#define MFMA(a,b,c) __builtin_amdgcn_mfma_f32_16x16x32_bf16(a,b,c,0,0,0)

#if __has_builtin(__builtin_amdgcn_exp2f)
#define EXP2(x) __builtin_amdgcn_exp2f(x)
#else
#define EXP2(x) exp2f(x)
#endif

__device__ __forceinline__ unsigned short f2bf(float f) {
  unsigned u = __builtin_bit_cast(unsigned, f);
  u += 0x7fffu + ((u >> 16) & 1u);   // RNE
  return (unsigned short)(u >> 16);
}

__device__ __forceinline__ bf16x8 ldfrag(const unsigned short* p) {
  return __builtin_bit_cast(bf16x8, *(const u16x8*)p);
}

// ---------------- fp32 -> bf16 convert ----------------
__global__ __launch_bounds__(256) void cvt_kernel(const float* __restrict__ src,
                                                  unsigned short* __restrict__ dst, int n4) {
  int i = blockIdx.x * blockDim.x + threadIdx.x;
  if (i >= n4) return;
  float4 f = ((const float4*)src)[i];
  u16x4 o;
  o[0] = f2bf(f.x); o[1] = f2bf(f.y); o[2] = f2bf(f.z); o[3] = f2bf(f.w);
  ((u16x4*)dst)[i] = o;
}

// ---------------- mask -> additive float table ----------------
__global__ __launch_bounds__(256) void mask_kernel(const int* __restrict__ m,
                                                   float* __restrict__ mf, int n) {
  int i = blockIdx.x * blockDim.x + threadIdx.x;
  if (i < n) mf[i] = m[i] ? 0.0f : -1e9f;
}

// ---------------- fused QKV projection: C = x @ Wqkv^T + b, scatter to Q/K/VT ----------------
__global__ __launch_bounds__(256) void qkv_gemm(const unsigned short* __restrict__ xbf,
                                                const unsigned short* __restrict__ wbf,   // 3072x1024 row-major
                                                const float* __restrict__ bq,
                                                const float* __restrict__ bk,
                                                const float* __restrict__ bv,
                                                unsigned short* __restrict__ Qo,   // [b][h][l][dk]
                                                unsigned short* __restrict__ Ko,   // [b][h][l][dk]
                                                unsigned short* __restrict__ VTo)  // [b][h][dk][l]
{
  __shared__ __attribute__((aligned(16))) unsigned short As[64*LDT];
  __shared__ __attribute__((aligned(16))) unsigned short Bs[64*LDT];
  const int tid  = threadIdx.x;
  const int wid  = tid >> 6;
  const int lane = tid & 63;
  const int lr   = lane & 15;
  const int lg   = lane >> 4;
  const int m0   = blockIdx.x * 64;
  const int n0   = blockIdx.y * 64;

  f32x4 zero = {0.f, 0.f, 0.f, 0.f};
  f32x4 acc[4];
  acc[0] = zero; acc[1] = zero; acc[2] = zero; acc[3] = zero;

  const int ko = lg * 8;
  for (int kt = 0; kt < D_MODEL/64; ++kt) {
    __syncthreads();
    for (int v = tid; v < 512; v += 256) {
      int row = v >> 3, c8 = (v & 7) * 8;
      *(u16x8*)&As[row*LDT + c8] = *(const u16x8*)&xbf[(size_t)(m0+row)*D_MODEL + kt*64 + c8];
      *(u16x8*)&Bs[row*LDT + c8] = *(const u16x8*)&wbf[(size_t)(n0+row)*D_MODEL + kt*64 + c8];
    }
    __syncthreads();
    bf16x8 a0 = ldfrag(&As[(wid*16+lr)*LDT + ko]);
    bf16x8 a1 = ldfrag(&As[(wid*16+lr)*LDT + 32 + ko]);
#pragma unroll
    for (int ct = 0; ct < 4; ++ct) {
      bf16x8 b0 = ldfrag(&Bs[(ct*16+lr)*LDT + ko]);
      bf16x8 b1 = ldfrag(&Bs[(ct*16+lr)*LDT + 32 + ko]);
      acc[ct] = MFMA(a0, b0, acc[ct]);
      acc[ct] = MFMA(a1, b1, acc[ct]);
    }
  }

  const int proj = n0 >> 10;            // block-uniform
  const int rem0 = n0 & 1023;           // h*64 (64-aligned)
  const int h    = rem0 >> 6;
  const float* bias = (proj == 0) ? bq : (proj == 1) ? bk : bv;

  if (proj < 2) {
    unsigned short* dst = (proj == 0) ? Qo : Ko;
#pragma unroll
    for (int ct = 0; ct < 4; ++ct) {
      int col = ct*16 + lr;             // dk
      float bval = bias[rem0 + col];
#pragma unroll
      for (int r = 0; r < 4; ++r) {
        int m  = m0 + wid*16 + lg*4 + r;
        int b_ = m >> 11, lq = m & (SEQ-1);
        dst[((size_t)((b_*NHEADS + h)*SEQ + lq))*DKH + col] = f2bf(acc[ct][r] + bval);
      }
    }
  } else {
    // transpose through LDS, then coalesced VT store
    __syncthreads();
#pragma unroll
    for (int ct = 0; ct < 4; ++ct) {
      int col = ct*16 + lr;             // dk
      float bval = bias[rem0 + col];
#pragma unroll
      for (int r = 0; r < 4; ++r) {
        int row = wid*16 + lg*4 + r;    // lq offset
        As[col*LDT + row] = f2bf(acc[ct][r] + bval);
      }
    }
    __syncthreads();
    int b_ = m0 >> 11, lq0 = m0 & (SEQ-1);
    int bh = b_*NHEADS + h;
    for (int v = tid; v < 512; v += 256) {
      int dk = v >> 3, c8 = (v & 7) * 8;
      *(u16x8*)&VTo[((size_t)(bh*DKH + dk))*SEQ + lq0 + c8] = *(const u16x8*)&As[dk*LDT + c8];
    }
  }
}

// ---------------- fused attention, barrier-free ----------------
// Swapped QK^T: MFMA(K_frag, Q_frag) -> S^T. Each lane owns one q row (lr) and
// 4 consecutive k per acc reg. All MFMA operands loaded directly from global
// (K row-major, VT pre-transposed, Q row-major -> every fragment is 16
// contiguous bytes). LDS used ONLY for the wave-local P transpose (no barriers
// anywhere: waves are fully independent).
__global__ __launch_bounds__(256) void attn_kernel(const unsigned short* __restrict__ Qw,
                                                   const unsigned short* __restrict__ Kw,
                                                   const unsigned short* __restrict__ VTw,
                                                   const float* __restrict__ maskf,   // 0 or -1e9 per (b,k)
                                                   float* __restrict__ attn_out,      // (B,H,L,L) fp32
                                                   unsigned short* __restrict__ OH)   // [b][l][h*64+dk] bf16
{
  __shared__ __attribute__((aligned(16))) unsigned short Ps[4*16*LDP];

  const int tid  = threadIdx.x;
  const int wid  = tid >> 6;
  const int lane = tid & 63;
  const int lr   = lane & 15;
  const int lg   = lane >> 4;
  const int q0   = blockIdx.x * 64;
  const int bh   = blockIdx.y;          // b*16+h
  const int b_   = bh >> 4;
  const int h    = bh & 15;

  const unsigned short* Qb = Qw  + (size_t)bh*SEQ*DKH;
  const unsigned short* Kb = Kw  + (size_t)bh*SEQ*DKH;
  const unsigned short* Vb = VTw + (size_t)bh*DKH*SEQ;
  const f32x4* mf4 = (const f32x4*)(maskf + b_*SEQ);

  // Q fragment, register-resident for the whole kernel (B-operand of swapped QK^T)
  const int qrow = q0 + wid*16 + lr;    // this lane's q row in S^T result space
  bf16x8 aq0 = ldfrag(&Qb[(size_t)qrow*DKH + lg*8]);
  bf16x8 aq1 = ldfrag(&Qb[(size_t)qrow*DKH + 32 + lg*8]);

  const float c2 = 0.18033688011112042f;   // 0.125 * log2(e); exp2(s*log2e) == exp(s)
  f32x4 zero = {0.f, 0.f, 0.f, 0.f};

  // per-lane base pointers (k-fragment row = lr within each 16-k subtile)
  const unsigned short* Kl = Kb + (size_t)lr*DKH + lg*8;

  // ---- pass 1: row sums of exp(S) ----
  float lsum = 0.f;
  for (int kt = 0; kt < SEQ/64; ++kt) {
    const unsigned short* Kt = Kl + (size_t)kt*64*DKH;
#pragma unroll
    for (int ct = 0; ct < 4; ++ct) {
      bf16x8 k0 = ldfrag(Kt + ct*16*DKH);
      bf16x8 k1 = ldfrag(Kt + ct*16*DKH + 32);
      f32x4 acc = zero;
      acc = MFMA(k0, aq0, acc);
      acc = MFMA(k1, aq1, acc);
      f32x4 md = mf4[kt*16 + ct*4 + lg];
#pragma unroll
      for (int r = 0; r < 4; ++r)
        lsum += EXP2(__builtin_fmaf(acc[r], c2, md[r]));
    }
  }
  lsum += __shfl_xor(lsum, 16);
  lsum += __shfl_xor(lsum, 32);
  const float il = 1.0f / lsum;

  // ---- pass 2: recompute S, write attn (float4, nontemporal), accumulate O ----
  f32x4 oacc[4];
  oacc[0] = zero; oacc[1] = zero; oacc[2] = zero; oacc[3] = zero;

  unsigned short* PsW = &Ps[wid*16*LDP];               // wave-private region
  float* arow = attn_out + ((size_t)bh*SEQ + qrow)*SEQ;
  const unsigned short* Vl = Vb + (size_t)lr*SEQ + lg*8;

  for (int kt = 0; kt < SEQ/64; ++kt) {
    const unsigned short* Kt = Kl + (size_t)kt*64*DKH;
#pragma unroll
    for (int ct = 0; ct < 4; ++ct) {
      bf16x8 k0 = ldfrag(Kt + ct*16*DKH);
      bf16x8 k1 = ldfrag(Kt + ct*16*DKH + 32);
      f32x4 acc = zero;
      acc = MFMA(k0, aq0, acc);
      acc = MFMA(k1, aq1, acc);
      f32x4 md = mf4[kt*16 + ct*4 + lg];
      f32x4 av;
#pragma unroll
      for (int r = 0; r < 4; ++r)
        av[r] = EXP2(__builtin_fmaf(acc[r], c2, md[r])) * il;
      // 16B store: k = kt*64 + ct*16 + lg*4 + [0..3], contiguous
      __builtin_nontemporal_store(av, (f32x4*)(arow + kt*64 + ct*16 + lg*4));
      // pack 4 bf16 of normalized P into wave-local transpose buffer
      u16x4 pk;
      pk[0] = f2bf(av[0]); pk[1] = f2bf(av[1]);
      pk[2] = f2bf(av[2]); pk[3] = f2bf(av[3]);
      *(u16x4*)&PsW[lr*LDP + ct*16 + lg*4] = pk;
    }
    // P fragment for PV (A-operand rows = q = lr); same-wave write->read, lgkmcnt only
    bf16x8 pa0 = ldfrag(&PsW[lr*LDP + lg*8]);
    bf16x8 pa1 = ldfrag(&PsW[lr*LDP + 32 + lg*8]);
    const unsigned short* Vt = Vl + kt*64;
#pragma unroll
    for (int ct = 0; ct < 4; ++ct) {
      bf16x8 v0 = ldfrag(Vt + (size_t)ct*16*SEQ);
      bf16x8 v1 = ldfrag(Vt + (size_t)ct*16*SEQ + 32);
      oacc[ct] = MFMA(pa0, v0, oacc[ct]);
      oacc[ct] = MFMA(pa1, v1, oacc[ct]);
    }
  }

  // write O tile as bf16 into OH (row-major 4096 x 1024, col = h*64+dk)
#pragma unroll
  for (int ct = 0; ct < 4; ++ct) {
    int dk = ct*16 + lr;
#pragma unroll
    for (int r = 0; r < 4; ++r) {
      int q = q0 + wid*16 + lg*4 + r;
      OH[(size_t)(b_*SEQ + q)*D_MODEL + h*DKH + dk] = f2bf(oacc[ct][r]);
    }
  }
}

// ---------------- output projection: out = OH @ Wo^T + bo (fp32 out) ----------------
__global__ __launch_bounds__(256) void out_gemm(const unsigned short* __restrict__ OH,
                                                const unsigned short* __restrict__ wo,
                                                const float* __restrict__ bo,
                                                float* __restrict__ out)
{
  __shared__ __attribute__((aligned(16))) unsigned short As[64*LDT];
  __shared__ __attribute__((aligned(16))) unsigned short Bs[64*LDT];
  const int tid  = threadIdx.x;
  const int wid  = tid >> 6;
  const int lane = tid & 63;
  const int lr   = lane & 15;
  const int lg   = lane >> 4;
  const int m0   = blockIdx.x * 64;
  const int n0   = blockIdx.y * 64;

  f32x4 zero = {0.f, 0.f, 0.f, 0.f};
  f32x4 acc[4];
  acc[0] = zero; acc[1] = zero; acc[2] = zero; acc[3] = zero;

  const int ko = lg * 8;
  for (int kt = 0; kt < D_MODEL/64; ++kt) {
    __syncthreads();
    for (int v = tid; v < 512; v += 256) {
      int row = v >> 3, c8 = (v & 7) * 8;
      *(u16x8*)&As[row*LDT + c8] = *(const u16x8*)&OH[(size_t)(m0+row)*D_MODEL + kt*64 + c8];
      *(u16x8*)&Bs[row*LDT + c8] = *(const u16x8*)&wo[(size_t)(n0+row)*D_MODEL + kt*64 + c8];
    }
    __syncthreads();
    bf16x8 a0 = ldfrag(&As[(wid*16+lr)*LDT + ko]);
    bf16x8 a1 = ldfrag(&As[(wid*16+lr)*LDT + 32 + ko]);
#pragma unroll
    for (int ct = 0; ct < 4; ++ct) {
      bf16x8 b0 = ldfrag(&Bs[(ct*16+lr)*LDT + ko]);
      bf16x8 b1 = ldfrag(&Bs[(ct*16+lr)*LDT + 32 + ko]);
      acc[ct] = MFMA(a0, b0, acc[ct]);
      acc[ct] = MFMA(a1, b1, acc[ct]);
    }
  }
#pragma unroll
  for (int ct = 0; ct < 4; ++ct) {
    int n = n0 + ct*16 + lr;
    float bval = bo[n];
#pragma unroll
    for (int r = 0; r < 4; ++r) {
      int m = m0 + wid*16 + lg*4 + r;
      out[(size_t)m*D_MODEL + n] = acc[ct][r] + bval;
    }
  }
}

extern "C" void kernel_launch(void* const* d_in, const int* in_sizes, int n_in,
                              void* d_out, int out_size, void* d_ws, size_t ws_size,
                              hipStream_t stream) {
  const float* x    = (const float*)d_in[0];
  const int*   mask = (const int*)  d_in[1];
  const float* Wq   = (const float*)d_in[2];
  const float* bq   = (const float*)d_in[3];
  const float* Wk   = (const float*)d_in[4];
  const float* bk   = (const float*)d_in[5];
  const float* Wv   = (const float*)d_in[6];
  const float* bv   = (const float*)d_in[7];
  const float* Wo   = (const float*)d_in[8];
  const float* bo   = (const float*)d_in[9];

  float* out0 = (float*)d_out;
  float* attn = out0 + (size_t)MTOT * D_MODEL;

  unsigned short* ws   = (unsigned short*)d_ws;
  unsigned short* xbf  = ws;                                   // 4096*1024
  unsigned short* wqkv = xbf  + (size_t)MTOT * D_MODEL;        // 3072*1024
  unsigned short* wob  = wqkv + (size_t)NQKV * D_MODEL;        // 1024*1024
  unsigned short* Qw   = wob  + (size_t)D_MODEL * D_MODEL;     // 4096*1024 (per-head)
  unsigned short* Kw   = Qw   + (size_t)MTOT * D_MODEL;
  unsigned short* VTw  = Kw   + (size_t)MTOT * D_MODEL;
  unsigned short* OH   = VTw  + (size_t)MTOT * D_MODEL;        // total 48 MiB

  // mask additive table reuses the (dead after qkv_gemm) xbf region
  float* maskf = (float*)xbf;

  // fp32 -> bf16 packs
  cvt_kernel<<<4096, 256, 0, stream>>>(x,  xbf, MTOT*D_MODEL/4);
  cvt_kernel<<<1024, 256, 0, stream>>>(Wq, wqkv,                 D_MODEL*D_MODEL/4);
  cvt_kernel<<<1024, 256, 0, stream>>>(Wk, wqkv +   D_MODEL*D_MODEL, D_MODEL*D_MODEL/4);
  cvt_kernel<<<1024, 256, 0, stream>>>(Wv, wqkv + 2*D_MODEL*D_MODEL, D_MODEL*D_MODEL/4);
  cvt_kernel<<<1024, 256, 0, stream>>>(Wo, wob, D_MODEL*D_MODEL/4);

  qkv_gemm<<<dim3(MTOT/64, NQKV/64), 256, 0, stream>>>(xbf, wqkv, bq, bk, bv, Qw, Kw, VTw);
  mask_kernel<<<16, 256, 0, stream>>>(mask, maskf, BATCH*SEQ);
  attn_kernel<<<dim3(SEQ/64, BATCH*NHEADS), 256, 0, stream>>>(Qw, Kw, VTw, maskf, attn, OH);
  out_gemm<<<dim3(MTOT/64, D_MODEL/64), 256, 0, stream>>>(OH, wob, bo, out0);
}

// Round 2
// 802.357 us; speedup vs baseline: 1.1704x; 1.1704x over previous
//
#include <hip/hip_runtime.h>

#define D_MODEL 1024
#define NHEADS  16
#define DKH     64
#define BATCH   2
#define SEQ     2048
#define MTOT    (BATCH*SEQ)     // 4096
#define NQKV    (3*D_MODEL)     // 3072
#define LDT     72              // 64 + 8 pad (ushorts) -> 144B row stride (GEMM kernels)
#define LDPF    68              // fp32 P-transpose LDS row stride (floats)

typedef __bf16 bf16x8 __attribute__((ext_vector_type(8)));
typedef float  f32x4  __attribute__((ext_vector_type(4)));
typedef unsigned short u16x8 __attribute__((ext_vector_type(8)));
typedef unsigned short u16x4 __attribute__((ext_vector_type(4)));

#define MFMA(a,b,c) __builtin_amdgcn_mfma_f32_16x16x32_bf16(a,b,c,0,0,0)

#if __has_builtin(__builtin_amdgcn_exp2f)
#define EXP2(x) __builtin_amdgcn_exp2f(x)
#else
#define EXP2(x) exp2f(x)
#endif

// async global->LDS, 16B per lane; dest = wave-uniform base + lane*16 (linear)
#define GLOAD_LDS16(g, l) __builtin_amdgcn_global_load_lds( \
    (const __attribute__((address_space(1))) unsigned int*)(g), \
    (__attribute__((address_space(3))) unsigned int*)(l), 16, 0, 0)

__device__ __forceinline__ unsigned short f2bf(float f) {
  unsigned u = __builtin_bit_cast(unsigned, f);
  u += 0x7fffu + ((u >> 16) & 1u);   // RNE
  return (unsigned short)(u >> 16);
}

__device__ __forceinline__ bf16x8 ldfrag(const unsigned short* p) {
  return __builtin_bit_cast(bf16x8, *(const u16x8*)p);
}

// read one MFMA fragment (8 ushorts) from a 64x64 XOR-swizzled LDS tile
__device__ __forceinline__ bf16x8 ldswz(const unsigned short* tile, int row, int chunk) {
  return ldfrag(tile + row*64 + ((chunk ^ (row & 7)) << 3));
}

// stage a 64x64 ushort tile (rows x 64) global->LDS with XOR-swizzled SOURCE,
// linear LDS dest. 256 threads cooperate; 512 chunks of 16B.
__device__ __forceinline__ void stage_tile(const unsigned short* __restrict__ gbase,
                                           size_t row_stride_us,
                                           unsigned short* lds_tile, int tid) {
#pragma unroll
  for (int it = 0; it < 2; ++it) {
    int chunk = it*256 + tid;
    int row = chunk >> 3, c = chunk & 7;
    int sc  = c ^ (row & 7);
    GLOAD_LDS16(gbase + (size_t)row*row_stride_us + sc*8, lds_tile + chunk*8);
  }
}

// ---------------- fp32 -> bf16 convert ----------------
__global__ __launch_bounds__(256) void cvt_kernel(const float* __restrict__ src,
                                                  unsigned short* __restrict__ dst, int n4) {
  int i = blockIdx.x * blockDim.x + threadIdx.x;
  if (i >= n4) return;
  float4 f = ((const float4*)src)[i];
  u16x4 o;
  o[0] = f2bf(f.x); o[1] = f2bf(f.y); o[2] = f2bf(f.z); o[3] = f2bf(f.w);
  ((u16x4*)dst)[i] = o;
}

// ---------------- mask -> additive float table ----------------
__global__ __launch_bounds__(256) void mask_kernel(const int* __restrict__ m,
                                                   float* __restrict__ mf, int n) {
  int i = blockIdx.x * blockDim.x + threadIdx.x;
  if (i < n) mf[i] = m[i] ? 0.0f : -1e9f;
}

// ---------------- fused QKV projection ----------------
__global__ __launch_bounds__(256) void qkv_gemm(const unsigned short* __restrict__ xbf,
                                                const unsigned short* __restrict__ wbf,
                                                const float* __restrict__ bq,
                                                const float* __restrict__ bk,
                                                const float* __restrict__ bv,
                                                unsigned short* __restrict__ Qo,
                                                unsigned short* __restrict__ Ko,
                                                unsigned short* __restrict__ VTo)
{
  __shared__ __attribute__((aligned(16))) unsigned short As[64*LDT];
  __shared__ __attribute__((aligned(16))) unsigned short Bs[64*LDT];
  const int tid  = threadIdx.x;
  const int wid  = tid >> 6;
  const int lane = tid & 63;
  const int lr   = lane & 15;
  const int lg   = lane >> 4;
  const int m0   = blockIdx.x * 64;
  const int n0   = blockIdx.y * 64;

  f32x4 zero = {0.f, 0.f, 0.f, 0.f};
  f32x4 acc[4];
  acc[0] = zero; acc[1] = zero; acc[2] = zero; acc[3] = zero;

  const int ko = lg * 8;
  for (int kt = 0; kt < D_MODEL/64; ++kt) {
    __syncthreads();
    for (int v = tid; v < 512; v += 256) {
      int row = v >> 3, c8 = (v & 7) * 8;
      *(u16x8*)&As[row*LDT + c8] = *(const u16x8*)&xbf[(size_t)(m0+row)*D_MODEL + kt*64 + c8];
      *(u16x8*)&Bs[row*LDT + c8] = *(const u16x8*)&wbf[(size_t)(n0+row)*D_MODEL + kt*64 + c8];
    }
    __syncthreads();
    bf16x8 a0 = ldfrag(&As[(wid*16+lr)*LDT + ko]);
    bf16x8 a1 = ldfrag(&As[(wid*16+lr)*LDT + 32 + ko]);
#pragma unroll
    for (int ct = 0; ct < 4; ++ct) {
      bf16x8 b0 = ldfrag(&Bs[(ct*16+lr)*LDT + ko]);
      bf16x8 b1 = ldfrag(&Bs[(ct*16+lr)*LDT + 32 + ko]);
      acc[ct] = MFMA(a0, b0, acc[ct]);
      acc[ct] = MFMA(a1, b1, acc[ct]);
    }
  }

  const int proj = n0 >> 10;
  const int rem0 = n0 & 1023;
  const int h    = rem0 >> 6;
  const float* bias = (proj == 0) ? bq : (proj == 1) ? bk : bv;

  if (proj < 2) {
    unsigned short* dst = (proj == 0) ? Qo : Ko;
#pragma unroll
    for (int ct = 0; ct < 4; ++ct) {
      int col = ct*16 + lr;
      float bval = bias[rem0 + col];
#pragma unroll
      for (int r = 0; r < 4; ++r) {
        int m  = m0 + wid*16 + lg*4 + r;
        int b_ = m >> 11, lq = m & (SEQ-1);
        dst[((size_t)((b_*NHEADS + h)*SEQ + lq))*DKH + col] = f2bf(acc[ct][r] + bval);
      }
    }
  } else {
    __syncthreads();
#pragma unroll
    for (int ct = 0; ct < 4; ++ct) {
      int col = ct*16 + lr;
      float bval = bias[rem0 + col];
#pragma unroll
      for (int r = 0; r < 4; ++r) {
        int row = wid*16 + lg*4 + r;
        As[col*LDT + row] = f2bf(acc[ct][r] + bval);
      }
    }
    __syncthreads();
    int b_ = m0 >> 11, lq0 = m0 & (SEQ-1);
    int bh = b_*NHEADS + h;
    for (int v = tid; v < 512; v += 256) {
      int dk = v >> 3, c8 = (v & 7) * 8;
      *(u16x8*)&VTo[((size_t)(bh*DKH + dk))*SEQ + lq0 + c8] = *(const u16x8*)&As[dk*LDT + c8];
    }
  }
}

// ---------------- fused attention ----------------
// Swapped QK^T (lane owns one q row) + block-shared double-buffered LDS K/V
// staged via global_load_lds (XOR-swizzled source, linear dest, swizzled read).
// attn stores coalesced through a wave-private fp32 LDS transpose.
__global__ __launch_bounds__(256) void attn_kernel(const unsigned short* __restrict__ Qw,
                                                   const unsigned short* __restrict__ Kw,
                                                   const unsigned short* __restrict__ VTw,
                                                   const float* __restrict__ maskf,
                                                   float* __restrict__ attn_out,
                                                   unsigned short* __restrict__ OH)
{
  __shared__ __attribute__((aligned(16))) unsigned short Ks[2][64*64];
  __shared__ __attribute__((aligned(16))) unsigned short Vs[2][64*64];
  __shared__ __attribute__((aligned(16))) float Pf[4][16*LDPF];

  const int tid  = threadIdx.x;
  const int wid  = tid >> 6;
  const int lane = tid & 63;
  const int lr   = lane & 15;
  const int lg   = lane >> 4;
  const int q0   = blockIdx.x * 64;
  const int bh   = blockIdx.y;          // b*16+h
  const int b_   = bh >> 4;
  const int h    = bh & 15;

  const unsigned short* Qb = Qw  + (size_t)bh*SEQ*DKH;
  const unsigned short* Kb = Kw  + (size_t)bh*SEQ*DKH;
  const unsigned short* Vb = VTw + (size_t)bh*DKH*SEQ;
  const f32x4* mf4 = (const f32x4*)(maskf + b_*SEQ);

  // Q fragment, register-resident (B-operand of swapped QK^T)
  const int qrow = q0 + wid*16 + lr;
  bf16x8 aq0 = ldfrag(&Qb[(size_t)qrow*DKH + lg*8]);
  bf16x8 aq1 = ldfrag(&Qb[(size_t)qrow*DKH + 32 + lg*8]);

  const float c2 = 0.18033688011112042f;   // 0.125 * log2(e)
  f32x4 zero = {0.f, 0.f, 0.f, 0.f};

  // ---- pass 1: row sums of exp(S) ----
  float lsum = 0.f;
  stage_tile(Kb, DKH, Ks[0], tid);
  __syncthreads();
  for (int kt = 0; kt < SEQ/64; ++kt) {
    int cur = kt & 1;
    if (kt < SEQ/64 - 1)
      stage_tile(Kb + (size_t)(kt+1)*64*DKH, DKH, Ks[cur^1], tid);
#pragma unroll
    for (int ct = 0; ct < 4; ++ct) {
      int row = ct*16 + lr;
      bf16x8 k0 = ldswz(Ks[cur], row, lg);
      bf16x8 k1 = ldswz(Ks[cur], row, lg + 4);
      f32x4 acc = zero;
      acc = MFMA(k0, aq0, acc);
      acc = MFMA(k1, aq1, acc);
      f32x4 md = mf4[kt*16 + ct*4 + lg];
#pragma unroll
      for (int r = 0; r < 4; ++r)
        lsum += EXP2(__builtin_fmaf(acc[r], c2, md[r]));
    }
    __syncthreads();   // compiler drains vmcnt here -> staged tile ready
  }
  lsum += __shfl_xor(lsum, 16);
  lsum += __shfl_xor(lsum, 32);
  const float il = 1.0f / lsum;

  // ---- pass 2: recompute S, coalesced attn store, accumulate O ----
  f32x4 oacc[4];
  oacc[0] = zero; oacc[1] = zero; oacc[2] = zero; oacc[3] = zero;

  float* PfW = Pf[wid];                 // wave-private
  float* arow0 = attn_out + ((size_t)bh*SEQ + q0 + wid*16)*SEQ;

  stage_tile(Kb, DKH, Ks[0], tid);
  stage_tile(Vb, SEQ, Vs[0], tid);
  __syncthreads();
  for (int kt = 0; kt < SEQ/64; ++kt) {
    int cur = kt & 1;
    if (kt < SEQ/64 - 1) {
      stage_tile(Kb + (size_t)(kt+1)*64*DKH, DKH, Ks[cur^1], tid);
      stage_tile(Vb + (size_t)(kt+1)*64,     SEQ, Vs[cur^1], tid);
    }
    // S^T tile + normalized P into wave-private fp32 transpose buffer
#pragma unroll
    for (int ct = 0; ct < 4; ++ct) {
      int row = ct*16 + lr;
      bf16x8 k0 = ldswz(Ks[cur], row, lg);
      bf16x8 k1 = ldswz(Ks[cur], row, lg + 4);
      f32x4 acc = zero;
      acc = MFMA(k0, aq0, acc);
      acc = MFMA(k1, aq1, acc);
      f32x4 md = mf4[kt*16 + ct*4 + lg];
      f32x4 av;
#pragma unroll
      for (int r = 0; r < 4; ++r)
        av[r] = EXP2(__builtin_fmaf(acc[r], c2, md[r])) * il;
      *(f32x4*)&PfW[lr*LDPF + ct*16 + lg*4] = av;   // lane's q row = lr
    }
    // coalesced attn store: 4 instrs, each 4 rows x 256B contiguous
#pragma unroll
    for (int i = 0; i < 4; ++i) {
      int r16 = i*4 + lg;
      f32x4 v = *(const f32x4*)&PfW[r16*LDPF + lr*4];
      *(f32x4*)(arow0 + (size_t)r16*SEQ + kt*64 + lr*4) = v;
    }
    // PV fragments from Pf (fp32 -> bf16), then O accumulate
    {
      const float* pp = &PfW[lr*LDPF];
      f32x4 p0 = *(const f32x4*)(pp + lg*8);
      f32x4 p1 = *(const f32x4*)(pp + lg*8 + 4);
      f32x4 p2 = *(const f32x4*)(pp + 32 + lg*8);
      f32x4 p3 = *(const f32x4*)(pp + 32 + lg*8 + 4);
      u16x8 w0, w1;
#pragma unroll
      for (int j = 0; j < 4; ++j) {
        w0[j]   = f2bf(p0[j]); w0[j+4] = f2bf(p1[j]);
        w1[j]   = f2bf(p2[j]); w1[j+4] = f2bf(p3[j]);
      }
      bf16x8 pa0 = __builtin_bit_cast(bf16x8, w0);
      bf16x8 pa1 = __builtin_bit_cast(bf16x8, w1);
#pragma unroll
      for (int ct = 0; ct < 4; ++ct) {
        int row = ct*16 + lr;
        bf16x8 v0 = ldswz(Vs[cur], row, lg);
        bf16x8 v1 = ldswz(Vs[cur], row, lg + 4);
        oacc[ct] = MFMA(pa0, v0, oacc[ct]);
        oacc[ct] = MFMA(pa1, v1, oacc[ct]);
      }
    }
    __syncthreads();
  }

  // write O tile as bf16 into OH
#pragma unroll
  for (int ct = 0; ct < 4; ++ct) {
    int dk = ct*16 + lr;
#pragma unroll
    for (int r = 0; r < 4; ++r) {
      int q = q0 + wid*16 + lg*4 + r;
      OH[(size_t)(b_*SEQ + q)*D_MODEL + h*DKH + dk] = f2bf(oacc[ct][r]);
    }
  }
}

// ---------------- output projection ----------------
__global__ __launch_bounds__(256) void out_gemm(const unsigned short* __restrict__ OH,
                                                const unsigned short* __restrict__ wo,
                                                const float* __restrict__ bo,
                                                float* __restrict__ out)
{
  __shared__ __attribute__((aligned(16))) unsigned short As[64*LDT];
  __shared__ __attribute__((aligned(16))) unsigned short Bs[64*LDT];
  const int tid  = threadIdx.x;
  const int wid  = tid >> 6;
  const int lane = tid & 63;
  const int lr   = lane & 15;
  const int lg   = lane >> 4;
  const int m0   = blockIdx.x * 64;
  const int n0   = blockIdx.y * 64;

  f32x4 zero = {0.f, 0.f, 0.f, 0.f};
  f32x4 acc[4];
  acc[0] = zero; acc[1] = zero; acc[2] = zero; acc[3] = zero;

  const int ko = lg * 8;
  for (int kt = 0; kt < D_MODEL/64; ++kt) {
    __syncthreads();
    for (int v = tid; v < 512; v += 256) {
      int row = v >> 3, c8 = (v & 7) * 8;
      *(u16x8*)&As[row*LDT + c8] = *(const u16x8*)&OH[(size_t)(m0+row)*D_MODEL + kt*64 + c8];
      *(u16x8*)&Bs[row*LDT + c8] = *(const u16x8*)&wo[(size_t)(n0+row)*D_MODEL + kt*64 + c8];
    }
    __syncthreads();
    bf16x8 a0 = ldfrag(&As[(wid*16+lr)*LDT + ko]);
    bf16x8 a1 = ldfrag(&As[(wid*16+lr)*LDT + 32 + ko]);
#pragma unroll
    for (int ct = 0; ct < 4; ++ct) {
      bf16x8 b0 = ldfrag(&Bs[(ct*16+lr)*LDT + ko]);
      bf16x8 b1 = ldfrag(&Bs[(ct*16+lr)*LDT + 32 + ko]);
      acc[ct] = MFMA(a0, b0, acc[ct]);
      acc[ct] = MFMA(a1, b1, acc[ct]);
    }
  }
#pragma unroll
  for (int ct = 0; ct < 4; ++ct) {
    int n = n0 + ct*16 + lr;
    float bval = bo[n];
#pragma unroll
    for (int r = 0; r < 4; ++r) {
      int m = m0 + wid*16 + lg*4 + r;
      out[(size_t)m*D_MODEL + n] = acc[ct][r] + bval;
    }
  }
}

extern "C" void kernel_launch(void* const* d_in, const int* in_sizes, int n_in,
                              void* d_out, int out_size, void* d_ws, size_t ws_size,
                              hipStream_t stream) {
  const float* x    = (const float*)d_in[0];
  const int*   mask = (const int*)  d_in[1];
  const float* Wq   = (const float*)d_in[2];
  const float* bq   = (const float*)d_in[3];
  const float* Wk   = (const float*)d_in[4];
  const float* bk   = (const float*)d_in[5];
  const float* Wv   = (const float*)d_in[6];
  const float* bv   = (const float*)d_in[7];
  const float* Wo   = (const float*)d_in[8];
  const float* bo   = (const float*)d_in[9];

  float* out0 = (float*)d_out;
  float* attn = out0 + (size_t)MTOT * D_MODEL;

  unsigned short* ws   = (unsigned short*)d_ws;
  unsigned short* xbf  = ws;
  unsigned short* wqkv = xbf  + (size_t)MTOT * D_MODEL;
  unsigned short* wob  = wqkv + (size_t)NQKV * D_MODEL;
  unsigned short* Qw   = wob  + (size_t)D_MODEL * D_MODEL;
  unsigned short* Kw   = Qw   + (size_t)MTOT * D_MODEL;
  unsigned short* VTw  = Kw   + (size_t)MTOT * D_MODEL;
  unsigned short* OH   = VTw  + (size_t)MTOT * D_MODEL;

  float* maskf = (float*)xbf;   // reuses xbf region AFTER qkv_gemm consumed it

  cvt_kernel<<<4096, 256, 0, stream>>>(x,  xbf, MTOT*D_MODEL/4);
  cvt_kernel<<<1024, 256, 0, stream>>>(Wq, wqkv,                 D_MODEL*D_MODEL/4);
  cvt_kernel<<<1024, 256, 0, stream>>>(Wk, wqkv +   D_MODEL*D_MODEL, D_MODEL*D_MODEL/4);
  cvt_kernel<<<1024, 256, 0, stream>>>(Wv, wqkv + 2*D_MODEL*D_MODEL, D_MODEL*D_MODEL/4);
  cvt_kernel<<<1024, 256, 0, stream>>>(Wo, wob, D_MODEL*D_MODEL/4);

  qkv_gemm<<<dim3(MTOT/64, NQKV/64), 256, 0, stream>>>(xbf, wqkv, bq, bk, bv, Qw, Kw, VTw);
  mask_kernel<<<16, 256, 0, stream>>>(mask, maskf, BATCH*SEQ);
  attn_kernel<<<dim3(SEQ/64, BATCH*NHEADS), 256, 0, stream>>>(Qw, Kw, VTw, maskf, attn, OH);
  out_gemm<<<dim3(MTOT/64, D_MODEL/64), 256, 0, stream>>>(OH, wob, bo, out0);
}

// Round 3
// 688.073 us; speedup vs baseline: 1.3648x; 1.1661x over previous
//
#include <hip/hip_runtime.h>

#define D_MODEL 1024
#define NHEADS  16
#define DKH     64
#define BATCH   2
#define SEQ     2048
#define MTOT    (BATCH*SEQ)     // 4096
#define NQKV    (3*D_MODEL)     // 3072

typedef __bf16 bf16x8 __attribute__((ext_vector_type(8)));
typedef float  f32x4  __attribute__((ext_vector_type(4)));
typedef unsigned short u16x8 __attribute__((ext_vector_type(8)));
typedef unsigned short u16x4 __attribute__((ext_vector_type(4)));

#define MFMA(a,b,c) __builtin_amdgcn_mfma_f32_16x16x32_bf16(a,b,c,0,0,0)

#if __has_builtin(__builtin_amdgcn_exp2f)
#define EXP2(x) __builtin_amdgcn_exp2f(x)
#else
#define EXP2(x) exp2f(x)
#endif

// async global->LDS, 16B per lane; dest = wave-uniform base + lane*16 (linear)
#define GLOAD_LDS16(g, l) __builtin_amdgcn_global_load_lds( \
    (const __attribute__((address_space(1))) unsigned int*)(g), \
    (__attribute__((address_space(3))) unsigned int*)(l), 16, 0, 0)

__device__ __forceinline__ unsigned short f2bf(float f) {
  __bf16 h = (__bf16)f;                       // RNE via v_cvt
  return __builtin_bit_cast(unsigned short, h);
}

__device__ __forceinline__ bf16x8 ldfrag(const unsigned short* p) {
  return __builtin_bit_cast(bf16x8, *(const u16x8*)p);
}

// read one MFMA fragment (8 ushorts) from a [rows][64] XOR-swizzled LDS tile
__device__ __forceinline__ bf16x8 ldswz(const unsigned short* tile, int row, int chunk) {
  return ldfrag(tile + row*64 + ((chunk ^ (row & 7)) << 3));
}

// stage a 64x64 ushort tile global->LDS, XOR-swizzled SOURCE + linear dest
__device__ __forceinline__ void stage_tile(const unsigned short* __restrict__ gbase,
                                           size_t row_stride_us,
                                           unsigned short* lds_tile, int tid) {
#pragma unroll
  for (int it = 0; it < 2; ++it) {
    int chunk = it*256 + tid;
    int row = chunk >> 3, c = chunk & 7;
    int sc  = c ^ (row & 7);
    GLOAD_LDS16(gbase + (size_t)row*row_stride_us + sc*8, lds_tile + chunk*8);
  }
}

// ---------------- fp32 -> bf16 convert ----------------
__global__ __launch_bounds__(256) void cvt_kernel(const float* __restrict__ src,
                                                  unsigned short* __restrict__ dst, int n4) {
  int i = blockIdx.x * blockDim.x + threadIdx.x;
  if (i >= n4) return;
  float4 f = ((const float4*)src)[i];
  u16x4 o;
  o[0] = f2bf(f.x); o[1] = f2bf(f.y); o[2] = f2bf(f.z); o[3] = f2bf(f.w);
  ((u16x4*)dst)[i] = o;
}

// ---------------- mask -> additive float table ----------------
__global__ __launch_bounds__(256) void mask_kernel(const int* __restrict__ m,
                                                   float* __restrict__ mf, int n) {
  int i = blockIdx.x * blockDim.x + threadIdx.x;
  if (i < n) mf[i] = m[i] ? 0.0f : -1e9f;
}

// ---------------- shared 128x128 BT-GEMM core (m97 structure) ----------------
// C[128x128] = A[m0.., K] @ B[n0.., K]^T, K = 1024. 4 waves in 2x2 grid,
// each wave a 64x64 quadrant: acc[4][4] of 16x16 frags. Single-buffered LDS,
// global_load_lds width 16, swizzled source + swizzled read.
__device__ __forceinline__ void gemm128_bt(const unsigned short* __restrict__ A,
                                           const unsigned short* __restrict__ B,
                                           unsigned short* SB,   // 16384 ushorts
                                           int m0, int n0, int tid,
                                           f32x4 (&acc)[4][4])
{
  unsigned short* As = SB;            // 128x64
  unsigned short* Bs = SB + 8192;     // 128x64
  const int lane = tid & 63;
  const int lr   = lane & 15;
  const int lg   = lane >> 4;
  const int wid  = tid >> 6;
  const int wr   = wid >> 1;
  const int wc   = wid & 1;

  for (int kt = 0; kt < D_MODEL/64; ++kt) {
    __syncthreads();
#pragma unroll
    for (int it = 0; it < 4; ++it) {
      int chunk = it*256 + tid;            // 0..1023
      int row = chunk >> 3, c = chunk & 7, sc = c ^ (row & 7);
      GLOAD_LDS16(A + (size_t)(m0+row)*D_MODEL + kt*64 + sc*8, As + chunk*8);
      GLOAD_LDS16(B + (size_t)(n0+row)*D_MODEL + kt*64 + sc*8, Bs + chunk*8);
    }
    __syncthreads();
    bf16x8 a[4][2], b[4][2];
#pragma unroll
    for (int i = 0; i < 4; ++i) {
      int ra = wr*64 + i*16 + lr;
      int rb = wc*64 + i*16 + lr;
      a[i][0] = ldswz(As, ra, lg);  a[i][1] = ldswz(As, ra, lg + 4);
      b[i][0] = ldswz(Bs, rb, lg);  b[i][1] = ldswz(Bs, rb, lg + 4);
    }
#pragma unroll
    for (int i = 0; i < 4; ++i)
#pragma unroll
      for (int j = 0; j < 4; ++j) {
        acc[i][j] = MFMA(a[i][0], b[j][0], acc[i][j]);
        acc[i][j] = MFMA(a[i][1], b[j][1], acc[i][j]);
      }
  }
  __syncthreads();   // SB free for epilogue reuse
}

// ---------------- fused QKV projection (128x128 tiles) ----------------
__global__ __launch_bounds__(256) void qkv_gemm(const unsigned short* __restrict__ xbf,
                                                const unsigned short* __restrict__ wbf,
                                                const float* __restrict__ bq,
                                                const float* __restrict__ bk,
                                                const float* __restrict__ bv,
                                                unsigned short* __restrict__ Qo,
                                                unsigned short* __restrict__ Ko,
                                                unsigned short* __restrict__ VTo)
{
  __shared__ __attribute__((aligned(16))) unsigned short SB[16384];
  const int tid  = threadIdx.x;
  const int lane = tid & 63, lr = lane & 15, lg = lane >> 4;
  const int wid  = tid >> 6, wr = wid >> 1, wc = wid & 1;
  const int m0   = blockIdx.x * 128;
  const int n0   = blockIdx.y * 128;

  f32x4 acc[4][4];
#pragma unroll
  for (int i = 0; i < 4; ++i)
#pragma unroll
    for (int j = 0; j < 4; ++j) acc[i][j] = f32x4{0.f,0.f,0.f,0.f};

  gemm128_bt(xbf, wbf, SB, m0, n0, tid, acc);

  const int proj  = n0 >> 10;           // block-uniform
  const int rem0  = n0 & 1023;
  const int hbase = rem0 >> 6;          // tile spans heads hbase, hbase+1
  const int b_    = m0 >> 11;           // tile within one batch (2048 % 128 == 0)
  const int lq0   = m0 & (SEQ-1);
  const float* bias = (proj == 0) ? bq : (proj == 1) ? bk : bv;

  if (proj < 2) {
    unsigned short* dst = (proj == 0) ? Qo : Ko;
    // bounce C through LDS: [row][col] bf16, 16B-slot swizzled by row
#pragma unroll
    for (int i = 0; i < 4; ++i)
#pragma unroll
      for (int j = 0; j < 4; ++j) {
        int col = wc*64 + j*16 + lr;
        float bval = bias[rem0 + col];
        int slot = col >> 3, ce = col & 7;
#pragma unroll
        for (int r = 0; r < 4; ++r) {
          int row = wr*64 + i*16 + lg*4 + r;
          SB[row*128 + ((slot ^ (row & 15)) << 3) + ce] = f2bf(acc[i][j][r] + bval);
        }
      }
    __syncthreads();
#pragma unroll
    for (int it = 0; it < 8; ++it) {
      int v = it*256 + tid;             // 128 rows x 16 slots
      int row = v >> 4, slot = v & 15;
      u16x8 val = *(const u16x8*)&SB[row*128 + ((slot ^ (row & 15)) << 3)];
      int h = hbase + (slot >> 3), dk8 = (slot & 7)*8;
      int lq = lq0 + row;
      *(u16x8*)&dst[((size_t)((b_*NHEADS + h)*SEQ + lq))*DKH + dk8] = val;
    }
  } else {
    // V: transpose in LDS -> [c][lq] bf16, 16B-slot swizzled by c
#pragma unroll
    for (int i = 0; i < 4; ++i)
#pragma unroll
      for (int j = 0; j < 4; ++j) {
        int c = wc*64 + j*16 + lr;
        float bval = bias[rem0 + c];
#pragma unroll
        for (int r = 0; r < 4; ++r) {
          int lq = wr*64 + i*16 + lg*4 + r;
          SB[c*128 + (((lq >> 3) ^ (c & 15)) << 3) + (lq & 7)] = f2bf(acc[i][j][r] + bval);
        }
      }
    __syncthreads();
#pragma unroll
    for (int it = 0; it < 8; ++it) {
      int v = it*256 + tid;             // 128 cols x 16 slots
      int c = v >> 4, s = v & 15;
      u16x8 val = *(const u16x8*)&SB[c*128 + ((s ^ (c & 15)) << 3)];
      int bh = b_*NHEADS + hbase + (c >> 6), dk = c & 63;
      *(u16x8*)&VTo[((size_t)(bh*DKH + dk))*SEQ + lq0 + s*8] = val;
    }
  }
}

// ---------------- fused attention ----------------
// Swapped QK^T + dbuf LDS K/V via global_load_lds; chunked XOR-swizzled
// wave-private Pf (fp32) for coalesced attn stores + PV fragments.
// LDS = 40960 B exactly -> 4 blocks/CU, grid 1024 = exact fill.
__global__ __launch_bounds__(256) void attn_kernel(const unsigned short* __restrict__ Qw,
                                                   const unsigned short* __restrict__ Kw,
                                                   const unsigned short* __restrict__ VTw,
                                                   const float* __restrict__ maskf,
                                                   float* __restrict__ attn_out,
                                                   unsigned short* __restrict__ OH)
{
  __shared__ __attribute__((aligned(16))) unsigned short S[20480];   // 40 KB
  unsigned short* K0 = S;
  unsigned short* K1 = S + 4096;
  unsigned short* V0 = S + 8192;
  unsigned short* V1 = S + 12288;
  float* Pf = (float*)(S + 16384);      // 4 waves x 16 x 32 floats

  const int tid  = threadIdx.x;
  const int wid  = tid >> 6;
  const int lane = tid & 63;
  const int lr   = lane & 15;
  const int lg   = lane >> 4;

  // XCD-aware swizzle: same-head q-blocks land on one XCD (K/V = 1MB, 4 heads/XCD L2)
  const int flat = blockIdx.y * gridDim.x + blockIdx.x;   // 1024 blocks
  const int nf   = (flat & 7)*128 + (flat >> 3);          // bijective (1024 % 8 == 0)
  const int q0   = (nf & 31) * 64;
  const int bh   = nf >> 5;             // b*16+h
  const int b_   = bh >> 4;
  const int h    = bh & 15;

  const unsigned short* Qb = Qw  + (size_t)bh*SEQ*DKH;
  const unsigned short* Kb = Kw  + (size_t)bh*SEQ*DKH;
  const unsigned short* Vb = VTw + (size_t)bh*DKH*SEQ;
  const f32x4* mf4 = (const f32x4*)(maskf + b_*SEQ);

  const int qrow = q0 + wid*16 + lr;    // this lane's q row
  bf16x8 aq0 = ldfrag(&Qb[(size_t)qrow*DKH + lg*8]);
  bf16x8 aq1 = ldfrag(&Qb[(size_t)qrow*DKH + 32 + lg*8]);

  const float SCL = 0.18033688011112042f;   // 0.125 * log2(e)
  f32x4 zero = {0.f, 0.f, 0.f, 0.f};

  // ---- pass 1: row sums of exp(S) ----
  float lsum = 0.f;
  stage_tile(Kb, DKH, K0, tid);
  __syncthreads();
  for (int kt = 0; kt < SEQ/64; ++kt) {
    unsigned short* cur = (kt & 1) ? K1 : K0;
    unsigned short* nxt = (kt & 1) ? K0 : K1;
    if (kt < SEQ/64 - 1)
      stage_tile(Kb + (size_t)(kt+1)*64*DKH, DKH, nxt, tid);
#pragma unroll
    for (int ct = 0; ct < 4; ++ct) {
      int row = ct*16 + lr;
      bf16x8 k0 = ldswz(cur, row, lg);
      bf16x8 k1 = ldswz(cur, row, lg + 4);
      f32x4 acc = zero;
      acc = MFMA(k0, aq0, acc);
      acc = MFMA(k1, aq1, acc);
      f32x4 md = mf4[kt*16 + ct*4 + lg];
#pragma unroll
      for (int r = 0; r < 4; ++r)
        lsum += EXP2(__builtin_fmaf(acc[r], SCL, md[r]));
    }
    __syncthreads();   // drains staged tile
  }
  lsum += __shfl_xor(lsum, 16);
  lsum += __shfl_xor(lsum, 32);
  const float il = 1.0f / lsum;

  // ---- pass 2: recompute S, coalesced nt attn store, accumulate O ----
  f32x4 oacc[4];
  oacc[0] = zero; oacc[1] = zero; oacc[2] = zero; oacc[3] = zero;

  float* PfW = Pf + wid*512;            // wave-private 16x32, slot-swizzled
  float* arow0 = attn_out + ((size_t)bh*SEQ + q0 + wid*16)*SEQ;

  stage_tile(Kb, DKH, K0, tid);
  stage_tile(Vb, SEQ, V0, tid);
  __syncthreads();
  for (int kt = 0; kt < SEQ/64; ++kt) {
    unsigned short* Kc = (kt & 1) ? K1 : K0;
    unsigned short* Kn = (kt & 1) ? K0 : K1;
    unsigned short* Vc = (kt & 1) ? V1 : V0;
    unsigned short* Vn = (kt & 1) ? V0 : V1;
    if (kt < SEQ/64 - 1) {
      stage_tile(Kb + (size_t)(kt+1)*64*DKH, DKH, Kn, tid);
      stage_tile(Vb + (size_t)(kt+1)*64,     SEQ, Vn, tid);
    }
    bf16x8 pa0, pa1;
#pragma unroll
    for (int ch = 0; ch < 2; ++ch) {    // 32-k chunks, Pf reused per chunk
#pragma unroll
      for (int c2 = 0; c2 < 2; ++c2) {
        int ct = ch*2 + c2;
        int row = ct*16 + lr;
        bf16x8 k0 = ldswz(Kc, row, lg);
        bf16x8 k1 = ldswz(Kc, row, lg + 4);
        f32x4 acc = zero;
        acc = MFMA(k0, aq0, acc);
        acc = MFMA(k1, aq1, acc);
        f32x4 md = mf4[kt*16 + ct*4 + lg];
        f32x4 av;
#pragma unroll
        for (int r = 0; r < 4; ++r)
          av[r] = EXP2(__builtin_fmaf(acc[r], SCL, md[r])) * il;
        *(f32x4*)&PfW[lr*32 + (((c2*4 + lg) ^ (lr & 7)) << 2)] = av;
      }
      // coalesced attn store: 2 instrs, each 8 rows x 128B contiguous
#pragma unroll
      for (int i = 0; i < 2; ++i) {
        int row = i*8 + (lane >> 3), cs = lane & 7;
        f32x4 v = *(const f32x4*)&PfW[row*32 + ((cs ^ (row & 7)) << 2)];
        __builtin_nontemporal_store(v,
            (f32x4*)(arow0 + (size_t)row*SEQ + kt*64 + ch*32 + cs*4));
      }
      // PV fragment for this chunk (q=lr, k=ch*32+lg*8..+7)
      f32x4 r0 = *(const f32x4*)&PfW[lr*32 + (((lg*2    ) ^ (lr & 7)) << 2)];
      f32x4 r1 = *(const f32x4*)&PfW[lr*32 + (((lg*2 + 1) ^ (lr & 7)) << 2)];
      bf16x8 pa;
#pragma unroll
      for (int j = 0; j < 4; ++j) { pa[j] = (__bf16)r0[j]; pa[j+4] = (__bf16)r1[j]; }
      if (ch == 0) pa0 = pa; else pa1 = pa;
    }
    __builtin_amdgcn_s_setprio(1);
#pragma unroll
    for (int ct = 0; ct < 4; ++ct) {
      int row = ct*16 + lr;
      bf16x8 v0 = ldswz(Vc, row, lg);
      bf16x8 v1 = ldswz(Vc, row, lg + 4);
      oacc[ct] = MFMA(pa0, v0, oacc[ct]);
      oacc[ct] = MFMA(pa1, v1, oacc[ct]);
    }
    __builtin_amdgcn_s_setprio(0);
    __syncthreads();
  }

  // write O tile as bf16 into OH
#pragma unroll
  for (int ct = 0; ct < 4; ++ct) {
    int dk = ct*16 + lr;
#pragma unroll
    for (int r = 0; r < 4; ++r) {
      int q = q0 + wid*16 + lg*4 + r;
      OH[(size_t)(b_*SEQ + q)*D_MODEL + h*DKH + dk] = f2bf(oacc[ct][r]);
    }
  }
}

// ---------------- output projection (128x128 tiles) ----------------
__global__ __launch_bounds__(256) void out_gemm(const unsigned short* __restrict__ OH,
                                                const unsigned short* __restrict__ wo,
                                                const float* __restrict__ bo,
                                                float* __restrict__ out)
{
  __shared__ __attribute__((aligned(16))) unsigned short SB[16384];
  const int tid  = threadIdx.x;
  const int lane = tid & 63, lr = lane & 15, lg = lane >> 4;
  const int wid  = tid >> 6, wr = wid >> 1, wc = wid & 1;
  const int m0   = blockIdx.x * 128;
  const int n0   = blockIdx.y * 128;

  f32x4 acc[4][4];
#pragma unroll
  for (int i = 0; i < 4; ++i)
#pragma unroll
    for (int j = 0; j < 4; ++j) acc[i][j] = f32x4{0.f,0.f,0.f,0.f};

  gemm128_bt(OH, wo, SB, m0, n0, tid, acc);

#pragma unroll
  for (int i = 0; i < 4; ++i)
#pragma unroll
    for (int j = 0; j < 4; ++j) {
      int n = n0 + wc*64 + j*16 + lr;
      float bval = bo[n];
#pragma unroll
      for (int r = 0; r < 4; ++r) {
        int m = m0 + wr*64 + i*16 + lg*4 + r;
        out[(size_t)m*D_MODEL + n] = acc[i][j][r] + bval;
      }
    }
}

extern "C" void kernel_launch(void* const* d_in, const int* in_sizes, int n_in,
                              void* d_out, int out_size, void* d_ws, size_t ws_size,
                              hipStream_t stream) {
  const float* x    = (const float*)d_in[0];
  const int*   mask = (const int*)  d_in[1];
  const float* Wq   = (const float*)d_in[2];
  const float* bq   = (const float*)d_in[3];
  const float* Wk   = (const float*)d_in[4];
  const float* bk   = (const float*)d_in[5];
  const float* Wv   = (const float*)d_in[6];
  const float* bv   = (const float*)d_in[7];
  const float* Wo   = (const float*)d_in[8];
  const float* bo   = (const float*)d_in[9];

  float* out0 = (float*)d_out;
  float* attn = out0 + (size_t)MTOT * D_MODEL;

  unsigned short* ws   = (unsigned short*)d_ws;
  unsigned short* xbf  = ws;
  unsigned short* wqkv = xbf  + (size_t)MTOT * D_MODEL;
  unsigned short* wob  = wqkv + (size_t)NQKV * D_MODEL;
  unsigned short* Qw   = wob  + (size_t)D_MODEL * D_MODEL;
  unsigned short* Kw   = Qw   + (size_t)MTOT * D_MODEL;
  unsigned short* VTw  = Kw   + (size_t)MTOT * D_MODEL;
  unsigned short* OH   = VTw  + (size_t)MTOT * D_MODEL;

  float* maskf = (float*)xbf;   // reuses xbf region AFTER qkv_gemm consumed it

  cvt_kernel<<<4096, 256, 0, stream>>>(x,  xbf, MTOT*D_MODEL/4);
  cvt_kernel<<<1024, 256, 0, stream>>>(Wq, wqkv,                 D_MODEL*D_MODEL/4);
  cvt_kernel<<<1024, 256, 0, stream>>>(Wk, wqkv +   D_MODEL*D_MODEL, D_MODEL*D_MODEL/4);
  cvt_kernel<<<1024, 256, 0, stream>>>(Wv, wqkv + 2*D_MODEL*D_MODEL, D_MODEL*D_MODEL/4);
  cvt_kernel<<<1024, 256, 0, stream>>>(Wo, wob, D_MODEL*D_MODEL/4);

  qkv_gemm<<<dim3(MTOT/128, NQKV/128), 256, 0, stream>>>(xbf, wqkv, bq, bk, bv, Qw, Kw, VTw);
  mask_kernel<<<16, 256, 0, stream>>>(mask, maskf, BATCH*SEQ);
  attn_kernel<<<dim3(SEQ/64, BATCH*NHEADS), 256, 0, stream>>>(Qw, Kw, VTw, maskf, attn, OH);
  out_gemm<<<dim3(MTOT/128, D_MODEL/128), 256, 0, stream>>>(OH, wob, bo, out0);
}